// Round 18
// baseline (535.053 us; speedup 1.0000x reference)
//
#include <hip/hip_runtime.h>
#include <hip/hip_bf16.h>
#include <math.h>

#define BB 32
#define CC 64
#define C2 32
#define HH 32
#define WW 32
#define HW 1024
#define NTOT 3278
#define NPAD2 3328   // padded N (multiple of 128) for MFMA corr + fold
#define NT26 26      // NPAD2 / 128
#define NT64 52      // NPAD2 / 64  (k-tiles of the fold GEMM)

typedef __bf16   bf16x8 __attribute__((ext_vector_type(8)));
typedef _Float16 half8  __attribute__((ext_vector_type(8)));
typedef float    f32x4  __attribute__((ext_vector_type(4)));

__device__ __constant__ int SC_SIZE[5] = {32, 28, 25, 22, 19};
__device__ __constant__ int SC_OFF[6]  = {0, 1024, 1808, 2433, 2917, 3278};

// ---------------- fused feature kernel: LDS-staged, x read once ----------------
#define XS_STR 65
#define WS_STR 132
__global__ void __launch_bounds__(256, 1) k_feats(
        const float* __restrict__ x,
        const float* __restrict__ wb, const float* __restrict__ bb, const float* __restrict__ ab,
        const float* __restrict__ wm, const float* __restrict__ bm, const float* __restrict__ am,
        const float* __restrict__ wa, const float* __restrict__ ba, const float* __restrict__ aa,
        _Float16* __restrict__ mft, _Float16* __restrict__ rft,
        __bf16* __restrict__ basef,
        float* __restrict__ mbss, float* __restrict__ rmss) {
    __shared__ float Xs[64 * XS_STR];     // [c][p]
    __shared__ float Wls[64 * WS_STR];    // [c][o]
    __shared__ float bsh[128];
    __shared__ float ash3[3];
    int tid = threadIdx.x;
    int g0 = blockIdx.x * 64;
    int b = g0 >> 10, p0 = g0 & 1023;

    const float* xb = x + (size_t)b * CC * HW + p0;
    for (int i = tid; i < 64 * 64; i += 256) {
        int c = i >> 6, p = i & 63;
        Xs[c * XS_STR + p] = xb[(size_t)c * HW + p];
    }
    for (int i = tid; i < 128 * 64; i += 256) {
        int o = i >> 6, c = i & 63;
        float w = (o < 32) ? wb[o * CC + c] : (o < 64) ? wm[(o - 32) * CC + c] : wa[(o - 64) * CC + c];
        Wls[c * WS_STR + o] = w;
    }
    if (tid < 128) bsh[tid] = (tid < 32) ? bb[tid] : (tid < 64) ? bm[tid - 32] : ba[tid - 64];
    if (tid == 128) ash3[0] = ab[0];
    if (tid == 129) ash3[1] = am[0];
    if (tid == 130) ash3[2] = aa[0];
    __syncthreads();

    int p = tid & 63, og = tid >> 6;
    int o0 = og * 32;
    float acc[32];
#pragma unroll
    for (int oi = 0; oi < 32; ++oi) acc[oi] = bsh[o0 + oi];
    for (int c = 0; c < 64; ++c) {
        float xv = Xs[c * XS_STR + p];
        const float* wr = &Wls[c * WS_STR + o0];
#pragma unroll
        for (int oi = 0; oi < 32; ++oi) acc[oi] += wr[oi] * xv;
    }
    int pp = p0 + p;
    if (og < 2) {
        float alpha = ash3[og], ss = 0.f;
        half8 hv[4];
#pragma unroll
        for (int oi = 0; oi < 32; ++oi) {
            float v = acc[oi] >= 0.f ? acc[oi] : alpha * acc[oi];
            ss += v * v;
            hv[oi >> 3][oi & 7] = (_Float16)v;
        }
        _Float16* d = (og == 0 ? mft : rft) + ((size_t)b * HW + pp) * 32;
#pragma unroll
        for (int q = 0; q < 4; ++q) *(half8*)&d[q * 8] = hv[q];
        if (og == 0) mbss[(size_t)b * HW + pp] = ss;
        else         rmss[(size_t)b * HW + pp] = ss;
    } else {
        float alpha = ash3[2];
        int ob = o0 - 64;
#pragma unroll
        for (int oi = 0; oi < 32; ++oi) {
            float v = acc[oi] >= 0.f ? acc[oi] : alpha * acc[oi];
            basef[((size_t)b * CC + ob + oi) * HW + pp] = (__bf16)v;
        }
    }
}

// ---------------- neighbor table (+ zero pad for predicated gload_lds) ----------------
__global__ void k_nbr(int* __restrict__ nbr_pos, float* __restrict__ zpad) {
    if (blockIdx.x == 0 && threadIdx.x < 64) zpad[threadIdx.x] = 0.f;
    int n = blockIdx.x * blockDim.x + threadIdx.x;
    if (n >= NTOT) return;
    int s = 0;
    while (s < 4 && n >= SC_OFF[s + 1]) ++s;
    int q = n - SC_OFF[s];
    int hs = SC_SIZE[s];
    int ny = q / hs, nx = q % hs;
    for (int dy = 0; dy < 3; ++dy)
        for (int dx = 0; dx < 3; ++dx) {
            int yy = ny + dy - 1, xx = nx + dx - 1;
            int pos = -1;
            if (yy >= 0 && yy < hs && xx >= 0 && xx < hs)
                pos = ((yy * HH) / hs) * WW + (xx * WW) / hs;
            nbr_pos[(dy * 3 + dx) * NTOT + n] = pos;
        }
}

// ---------------- per-(b,p) logit upper bound ----------------
__global__ void k_qnorm(const float* __restrict__ mbss, float* __restrict__ qub) {
    int t = blockIdx.x * blockDim.x + threadIdx.x;
    int b = t >> 10, p = t & 1023;
    int y = p >> 5, x = p & 31;
    float s = 0.f;
#pragma unroll
    for (int dy = 0; dy < 3; ++dy)
#pragma unroll
        for (int dx = 0; dx < 3; ++dx) {
            int yy = y + dy - 1, xx = x + dx - 1;
            if (yy >= 0 && yy < HH && xx >= 0 && xx < WW)
                s += mbss[(size_t)b * HW + yy * WW + xx];
        }
    qub[t] = 10.0f * sqrtf(s);
}

// ---------------- per-(b,n) filter norms ----------------
__global__ void k_norms(const float* __restrict__ rmss, const int* __restrict__ nbr_pos,
                        float* __restrict__ sinv) {
    int t = blockIdx.x * blockDim.x + threadIdx.x;
    if (t >= BB * NTOT) return;
    int b = t / NTOT, n = t % NTOT;
    float sum = 0.f;
#pragma unroll
    for (int kk = 0; kk < 9; ++kk) {
        int pos = nbr_pos[kk * NTOT + n];
        if (pos >= 0) sum += rmss[(size_t)b * HW + pos];
    }
    sinv[t] = 10.0f / fmaxf(sqrtf(sum), 1e-4f);
}

// ---------------- V gather: LDS-staged basef row, tiled+swizzled Vb output ----------------
// Vb layout: Vb[((cb*NT64 + kt)*576 + m)*64 + j'] with j' = ((j/8) ^ (m&7))*8 + j%8
// R14 verified: XCD-affinity (cb -> XCD cb/(CB/8)) fills Vb into fold's L2.
__global__ void k_vgather(const __bf16* __restrict__ basef, const int* __restrict__ nbr_pos,
                          __bf16* __restrict__ Vb, int b0) {
    int c, cb;
    {
        int nCB = gridDim.y;
        int bid = blockIdx.x + CC * blockIdx.y;
        if ((nCB & 7) == 0) {
            int xcd = bid & 7, idx = bid >> 3;       // idx in [0, CC*nCB/8)
            int cpx = nCB >> 3;
            cb = xcd * cpx + idx / CC;
            c  = idx % CC;
        } else { c = blockIdx.x; cb = blockIdx.y; }
    }
    int tid = threadIdx.x;
    __shared__ __bf16 row[HW];    // one basef channel row, 2 KB
    const __bf16* src = basef + ((size_t)(b0 + cb) * CC + c) * HW;
    for (int i = tid; i < HW / 8; i += 256)
        *(bf16x8*)&row[i * 8] = *(const bf16x8*)&src[i * 8];
    __syncthreads();
    for (int t = tid; t < 9 * (NPAD2 / 8); t += 256) {
        int kk = t / (NPAD2 / 8), nq = t - kk * (NPAD2 / 8);
        int n0 = nq * 8;
        const int* nb = &nbr_pos[kk * NTOT];
        bf16x8 v8;
#pragma unroll
        for (int u = 0; u < 8; ++u) {
            int n = n0 + u;
            __bf16 v = (__bf16)0.f;
            if (n < NTOT) {
                int pos = nb[n];
                if (pos >= 0) v = row[pos];    // LDS gather, not global gather
            }
            v8[u] = v;
        }
        int m = c * 9 + kk;
        int nt = n0 >> 6;
        int j0s = (((n0 & 63) >> 3) ^ (m & 7)) << 3;
        *(bf16x8*)&Vb[(((size_t)cb * NT64 + nt) * 576 + m) * 64 + j0s] = v8;
    }
}

__device__ __forceinline__ void gload16(const void* g, void* l) {
    __builtin_amdgcn_global_load_lds(
        (const __attribute__((address_space(1))) void*)g,
        (__attribute__((address_space(3))) void*)l, 16, 0, 0);
}

// ---------------- correlation GEMM: fp16, 128p x 128n, DIRECT-STAGE gather ----------------
// R18: 3-BUFFER + COUNTED VMCNT (T4 at L2-latency regime). Accounting: issue-side
// work explains <20% of corr's 82us (220 cy/kk vs 2.1k measured) — the stall is
// the per-kk gather-landing chain: double-buffer gives stage(kk+1) only ONE
// compute phase (~250cy) vs L2 latency 300-500cy before the vmcnt(0) drain.
// Now: 3 buffers, per-iter top sync "s_waitcnt vmcnt(2); s_barrier" (vmcnt(0)
// at kk=8 only), stage(kk+2) issued AFTER the barrier (write-after-read safe:
// all readers of buf (kk-1)%3 passed this barrier; their ds_reads retired
// before their MFMAs issued). Stage kk gets TWO compute phases to land.
// LDS 49,152 -> 65,536 B (2 blocks/CU vs 3; trade TLP 24->16 waves against
// stall halving — loads are L2-resident, unlike R2's HBM regime).
// Falsifier: corr >= 80us => TLP loss dominates, revert and declare floor.
__global__ void __launch_bounds__(512) k_corr_mfma(
        const _Float16* __restrict__ mft, const _Float16* __restrict__ rft,
        const int* __restrict__ nbr_pos,
        const float* __restrict__ sinv, const float* __restrict__ qub,
        const float* __restrict__ zpad,
        __bf16* __restrict__ tbuf, float* __restrict__ partS, int b0) {
    int ptile, ntile, cb;
    {
        int nx = gridDim.x, ny = gridDim.y, nz = gridDim.z;     // 8, 26, CB
        int bid = blockIdx.x + nx * (blockIdx.y + ny * blockIdx.z);
        if ((nz & 7) == 0) {
            int xcd = bid & 7, idx = bid >> 3;
            int percb = nx * ny;               // 208
            int cpx = nz >> 3;
            cb = xcd * cpx + idx / percb;
            int r = idx % percb;
            ntile = r / nx;
            ptile = r % nx;
        } else { ptile = blockIdx.x; ntile = blockIdx.y; cb = blockIdx.z; }
    }
    int tid  = threadIdx.x;
    int lane = tid & 63, wave = tid >> 6;       // 8 waves
    int row16 = lane & 15, quad = lane >> 4;
    int wrP = wave >> 2, wrN = wave & 3;        // 2P x 4N wave grid (64p x 32n each)
    int p0 = ptile * 128, n0 = ntile * 128;

    __shared__ _Float16 Abuf[3][128 * 32];   // 3 x 8 KB  [row][32k], oct^(row&3) swizzle
    __shared__ _Float16 Bbuf[3][128 * 32];   // 3 x 8 KB
    __shared__ short nbrs[9][128];           // 2,304 B
    __shared__ short posA[9][128];           // 2,304 B
    __shared__ float sMub[128];              //   512 B
    __shared__ float redS[8][64];            // 2,048 B
    __shared__ __bf16 Tls[8][16 * 36];       // 9,216 B
                                             // total 65,536 B -> 2 blocks/CU

    if (tid < 128) sMub[tid] = qub[(size_t)(b0 + cb) * HW + p0 + tid];
    for (int i = tid; i < 9 * 128; i += 512) {
        int kk = i >> 7, j = i & 127;
        int n = n0 + j;
        nbrs[kk][j] = (short)((n < NTOT) ? nbr_pos[kk * NTOT + n] : -1);
        int pg = p0 + j;
        int py = (pg >> 5) + kk / 3 - 1, px = (pg & 31) + kk % 3 - 1;
        posA[kk][j] = (short)((py >= 0 && py < HH && px >= 0 && px < WW) ? (py * WW + px) : -1);
    }

    const char* mh = (const char*)(mft + (size_t)(b0 + cb) * HW * 32);
    const char* rh = (const char*)(rft + (size_t)(b0 + cb) * HW * 32);
    const char* zp = (const char*)zpad;

    f32x4 acc[4][2];
#pragma unroll
    for (int i = 0; i < 4; ++i)
#pragma unroll
        for (int j = 0; j < 2; ++j) acc[i][j] = (f32x4){0.f, 0.f, 0.f, 0.f};

    __syncthreads();   // tables ready (stage reads them from LDS)

    int srow = wave * 16 + (lane >> 2);          // this lane's staged row
    int sshift = (((lane & 3) ^ (srow & 3)) << 4);   // pre-swizzled src byte offset
    auto stageAB = [&](int sb, int kk) {
        int pa = posA[kk][srow];
        const char* sa = (pa >= 0) ? mh + (size_t)pa * 64 + sshift : zp;
        gload16(sa, (char*)&Abuf[sb][0] + wave * 1024);
        int pb = nbrs[kk][srow];
        const char* sbp = (pb >= 0) ? rh + (size_t)pb * 64 + sshift : zp;
        gload16(sbp, (char*)&Bbuf[sb][0] + wave * 1024);
    };

    stageAB(0, 0);     // 2 loads in flight
    stageAB(1, 1);     // 4 loads in flight
#pragma unroll
    for (int kk = 0; kk < 9; ++kk) {
        // Retire stage kk (oldest); keep stage kk+1 in flight (counted, never
        // drain-to-0 in the main loop). Barrier syncs all waves' retirements.
        if (kk < 8) asm volatile("s_waitcnt vmcnt(2)\n\ts_barrier" ::: "memory");
        else        asm volatile("s_waitcnt vmcnt(0)\n\ts_barrier" ::: "memory");
        // Issue stage kk+2 AFTER the barrier: its dest buf (kk-1)%3 has no
        // readers past this point (iter kk-1 compute finished pre-barrier).
        if (kk + 2 <= 8) stageAB((kk + 2) % 3, kk + 2);
        int cur = kk % 3;
        half8 af[4], bf[2];
#pragma unroll
        for (int m = 0; m < 4; ++m) {
            int row = wrP * 64 + m * 16 + row16;
            af[m] = *(const half8*)&Abuf[cur][row * 32 + ((quad ^ (row & 3)) << 3)];
        }
#pragma unroll
        for (int nb = 0; nb < 2; ++nb) {
            int row = wrN * 32 + nb * 16 + row16;
            bf[nb] = *(const half8*)&Bbuf[cur][row * 32 + ((quad ^ (row & 3)) << 3)];
        }
#pragma unroll
        for (int m = 0; m < 4; ++m)
#pragma unroll
            for (int nb = 0; nb < 2; ++nb)
                acc[m][nb] = __builtin_amdgcn_mfma_f32_16x16x32_f16(af[m], bf[nb], acc[m][nb], 0, 0, 0);
    }

    // ---- epilogue: v = acc*sinv[n]; t = exp(v - Mub[p]); Tls transpose -> 16B stores ----
    int nn[2];
    float sv[2];
    bool valid[2];
#pragma unroll
    for (int nb = 0; nb < 2; ++nb) {
        nn[nb] = n0 + wrN * 32 + nb * 16 + row16;
        valid[nb] = nn[nb] < NTOT;
        sv[nb] = valid[nb] ? sinv[(size_t)(b0 + cb) * NTOT + nn[nb]] : 0.f;
    }
    float sm[4][4];
#pragma unroll
    for (int m = 0; m < 4; ++m)
#pragma unroll
        for (int r = 0; r < 4; ++r) sm[m][r] = 0.f;

    int tr = lane >> 2, tc = (lane & 3) * 8;   // transpose-read coords (wave-local)
#pragma unroll
    for (int m = 0; m < 4; ++m) {
#pragma unroll
        for (int nb = 0; nb < 2; ++nb) {
#pragma unroll
            for (int r = 0; r < 4; ++r) {
                float mub = sMub[wrP * 64 + m * 16 + quad * 4 + r];
                float e = valid[nb] ? __expf(acc[m][nb][r] * sv[nb] - mub) : 0.f;
                Tls[wave][(quad * 4 + r) * 36 + nb * 16 + row16] = (__bf16)e;
                sm[m][r] += e;
            }
        }
        // wave-local consume (no block barrier needed)
        bf16x8 v = *(const bf16x8*)&Tls[wave][tr * 36 + tc];
        int nglob = n0 + wrN * 32 + tc;
        int nt = nglob >> 6, j0 = nglob & 63;
        int j0s = ((j0 >> 3) ^ (tr & 7)) << 3;   // p&7 == tr&7 (p0, wrP*64, m*16 all mult of 8)
        int p = p0 + wrP * 64 + m * 16 + tr;
        *(bf16x8*)&tbuf[(((size_t)cb * NT64 + nt) * HW + p) * 64 + j0s] = v;
    }

#pragma unroll
    for (int msk = 1; msk < 16; msk <<= 1)
#pragma unroll
        for (int m = 0; m < 4; ++m)
#pragma unroll
            for (int r = 0; r < 4; ++r) sm[m][r] += __shfl_xor(sm[m][r], msk, 64);
    if (row16 == 0)
#pragma unroll
        for (int m = 0; m < 4; ++m)
#pragma unroll
            for (int r = 0; r < 4; ++r) redS[wave][m * 16 + quad * 4 + r] = sm[m][r];
    __syncthreads();
    if ((wave == 0 || wave == 4) && row16 == 0) {
#pragma unroll
        for (int m = 0; m < 4; ++m)
#pragma unroll
            for (int r = 0; r < 4; ++r) {
                int p = m * 16 + quad * 4 + r;   // local within this wave's 64-p half
                float S = redS[wrP * 4 + 0][p] + redS[wrP * 4 + 1][p] +
                          redS[wrP * 4 + 2][p] + redS[wrP * 4 + 3][p];
                partS[((size_t)cb * HW + p0 + wrP * 64 + p) * NT26 + ntile] = S;
            }
    }
}

// ---------------- row sum reduce ----------------
__global__ void k_rowsum(const float* __restrict__ partS, float* __restrict__ fin) {
    int row = blockIdx.x * 256 + threadIdx.x;
    float s = 0.f;
#pragma unroll
    for (int nt = 0; nt < NT26; ++nt) s += partS[(size_t)row * NT26 + nt];
    fin[row] = 1.0f / fmaxf(s, 1e-38f);
}

// ---------------- fold GEMM (MFMA bf16), 192m x 128p + XCD-chunked swizzle ----------------
// FM=192 confirmed optimum (R16 A/B under affinity). Unchanged.
#define A_KSTRIDE (576 * 64 * 2)     // bytes per k-tile of Vb
#define B_KSTRIDE (1024 * 64 * 2)    // bytes per k-tile of tbuf
#define FM 192                        // fold tile m
#define FP 128                        // fold tile p

__global__ void __launch_bounds__(512, 4) k_fold_mfma(
        const __bf16* __restrict__ Vb, const __bf16* __restrict__ tbuf,
        const float* __restrict__ fin, __bf16* __restrict__ outacc) {
    int ptile, mtile, cb;
    {
        int nx = gridDim.x, ny = gridDim.y, nz = gridDim.z;
        int bid = blockIdx.x + nx * (blockIdx.y + ny * blockIdx.z);
        if ((nz & 7) == 0) {
            int xcd = bid & 7, idx = bid >> 3;
            int percb = nx * ny;              // blocks per cb (24)
            int cpx = nz >> 3;                // cbs per xcd
            cb = xcd * cpx + idx / percb;
            int r = idx % percb;
            mtile = r / nx;
            ptile = r % nx;
        } else {
            ptile = blockIdx.x; mtile = blockIdx.y; cb = blockIdx.z;
        }
    }
    int tid  = threadIdx.x;
    int lane = tid & 63, wave = tid >> 6;     // 8 waves
    int row16 = lane & 15, quad = lane >> 4;
    int wrM = wave >> 2, wrN = wave & 3;      // 2 x 4 wave grid: per-wave 96m x 32p

    __shared__ __bf16 Als[2][FM * 64];    // 2 x 24 KB
    __shared__ __bf16 Bls[2][FP * 64];    // 2 x 16 KB

    const char* Ag = (const char*)(Vb   + (((size_t)cb * NT64) * 576  + (size_t)mtile * FM) * 64);
    const char* Bg = (const char*)(tbuf + (((size_t)cb * NT64) * 1024 + (size_t)ptile * FP) * 64);

    f32x4 acc[6][2];
#pragma unroll
    for (int i = 0; i < 6; ++i)
#pragma unroll
        for (int j = 0; j < 2; ++j) acc[i][j] = (f32x4){0.f, 0.f, 0.f, 0.f};

    int lo16 = lane * 16;
    // A tile 24KB = 24 x 1KB chunks (8 rows each); B tile 16KB = 16 chunks.
    // 40 chunks / 8 waves = 5 per wave. Linear copy of pre-swizzled global.
    auto stage = [&](int sb, int kt) {
#pragma unroll
        for (int i = 0; i < 5; ++i) {
            int q = wave * 5 + i;
            if (q < 24) {
                gload16(Ag + (size_t)kt * A_KSTRIDE + q * 1024 + lo16,
                        (char*)&Als[sb][0] + q * 1024);
            } else {
                gload16(Bg + (size_t)kt * B_KSTRIDE + (q - 24) * 1024 + lo16,
                        (char*)&Bls[sb][0] + (q - 24) * 1024);
            }
        }
    };

    int sg = row16 & 7;   // row&7 for both A (m) and B (p) fragment rows
    auto compute = [&](int sb) {
#pragma unroll
        for (int kh = 0; kh < 2; ++kh) {
            int ko = ((kh * 4 + quad) ^ sg) << 3;
            bf16x8 af[6], bf[2];
#pragma unroll
            for (int mb = 0; mb < 6; ++mb)
                af[mb] = *(const bf16x8*)&Als[sb][(wrM * 96 + mb * 16 + row16) * 64 + ko];
#pragma unroll
            for (int pbi = 0; pbi < 2; ++pbi)
                bf[pbi] = *(const bf16x8*)&Bls[sb][(wrN * 32 + pbi * 16 + row16) * 64 + ko];
#pragma unroll
            for (int mb = 0; mb < 6; ++mb)
#pragma unroll
                for (int pbi = 0; pbi < 2; ++pbi)
                    acc[mb][pbi] = __builtin_amdgcn_mfma_f32_16x16x32_bf16(af[mb], bf[pbi], acc[mb][pbi], 0, 0, 0);
        }
    };

    stage(0, 0);
    __syncthreads();
    int cur = 0;
    for (int kt = 0; kt < NT64; ++kt) {
        if (kt + 1 < NT64) stage(cur ^ 1, kt + 1);   // in flight under ds_read+MFMA
        compute(cur);
        __syncthreads();   // drains vmcnt: next tile landed; buf cur free for kt+2
        cur ^= 1;
    }

    float fsc[2];
#pragma unroll
    for (int pbi = 0; pbi < 2; ++pbi)
        fsc[pbi] = fin[(size_t)cb * HW + ptile * FP + wrN * 32 + pbi * 16 + row16];
#pragma unroll
    for (int mb = 0; mb < 6; ++mb)
#pragma unroll
        for (int pbi = 0; pbi < 2; ++pbi) {
#pragma unroll
            for (int r = 0; r < 4; ++r) {
                int mg = mtile * FM + wrM * 96 + mb * 16 + quad * 4 + r;
                int pg = ptile * FP + wrN * 32 + pbi * 16 + row16;
                outacc[((size_t)cb * 576 + mg) * HW + pg] = (__bf16)(acc[mb][pbi][r] * fsc[pbi]);
            }
        }
}

// ---------------- epilogue (bf16 outacc) ----------------
// R14 verified: XCD-affinity so the 9-tap outacc reads hit fold's L2.
__global__ void k_epilogue(const float* __restrict__ x, const __bf16* __restrict__ outacc,
                           float* __restrict__ out, int b0) {
    int li, cb;
    {
        int nblk = gridDim.x;                 // CB * 256
        int nCB = nblk >> 8;
        int bid = blockIdx.x;
        if ((nCB & 7) == 0) {
            int xcd = bid & 7, idx = bid >> 3;    // idx in [0, nblk/8)
            int cpx = nCB >> 3;
            cb = xcd * cpx + idx / 256;
            li = (idx % 256) * 256 + threadIdx.x; // local index within cb
        } else {
            int t = bid * 256 + threadIdx.x;
            cb = t >> 16; li = t & 65535;
        }
    }
    int c = (li >> 10) & 63;
    int p = li & 1023;
    int b = b0 + cb;
    int y = p >> 5, xx = p & 31;
    float acc = 0.f;
#pragma unroll
    for (int ky = 0; ky < 3; ++ky)
#pragma unroll
        for (int kx = 0; kx < 3; ++kx) {
            int py = y + 1 - ky, px = xx + 1 - kx;
            if (py >= 0 && py < HH && px >= 0 && px < WW)
                acc += (float)outacc[((size_t)cb * 576 + c * 9 + ky * 3 + kx) * HW + py * WW + px];
        }
    size_t o = ((size_t)b * CC + c) * HW + p;
    out[o] = x[o] + 0.25f * acc;
}

extern "C" void kernel_launch(void* const* d_in, const int* in_sizes, int n_in,
                              void* d_out, int out_size, void* d_ws, size_t ws_size,
                              hipStream_t stream) {
    const float* x       = (const float*)d_in[0];
    const float* w_base  = (const float*)d_in[1];
    const float* b_base  = (const float*)d_in[2];
    const float* a_base  = (const float*)d_in[3];
    const float* w_match = (const float*)d_in[4];
    const float* b_match = (const float*)d_in[5];
    const float* a_match = (const float*)d_in[6];
    const float* w_asm   = (const float*)d_in[7];
    const float* b_asm   = (const float*)d_in[8];
    const float* a_asm   = (const float*)d_in[9];
    float* out = (float*)d_out;

    const size_t fixed = ((size_t)BB * HW * 32 * 2) * 2 + ((size_t)BB * CC * HW * 2) +
                         ((size_t)BB * HW * 4) * 3 + ((size_t)BB * NTOT * 4) +
                         ((size_t)9 * NTOT * 4) + 65536;
    const size_t perCB = ((size_t)HW * NPAD2 * 2) + ((size_t)HW * NT26 * 4) +
                         ((size_t)HW * 4) + ((size_t)576 * NPAD2 * 2) +
                         ((size_t)576 * HW * 2) + 65536;
    int CB = 32;
    while (CB > 1 && fixed + perCB * CB > ws_size) CB >>= 1;

    char* ws = (char*)d_ws;
    size_t off = 0;
    auto alloc_b = [&](size_t bytes) {
        void* p = (void*)(ws + off);
        off += bytes;
        off = (off + 255) & ~(size_t)255;
        return p;
    };
    _Float16* mft   = (_Float16*)alloc_b((size_t)BB * HW * 32 * 2);
    _Float16* rft   = (_Float16*)alloc_b((size_t)BB * HW * 32 * 2);
    __bf16* base_f  = (__bf16*)alloc_b((size_t)BB * CC * HW * 2);
    float*  mbss    = (float*)alloc_b((size_t)BB * HW * 4);
    float*  rmss    = (float*)alloc_b((size_t)BB * HW * 4);
    float*  qub     = (float*)alloc_b((size_t)BB * HW * 4);
    float*  sinv    = (float*)alloc_b((size_t)BB * NTOT * 4);
    int*    nbr_pos = (int*)alloc_b((size_t)9 * NTOT * 4);
    float*  zpad    = (float*)alloc_b(256);
    __bf16* tbuf    = (__bf16*)alloc_b((size_t)CB * HW * NPAD2 * 2);
    float*  partS   = (float*)alloc_b((size_t)CB * HW * NT26 * 4);
    float*  fin     = (float*)alloc_b((size_t)CB * HW * 4);
    __bf16* Vb      = (__bf16*)alloc_b((size_t)CB * 576 * NPAD2 * 2);
    __bf16* outacc  = (__bf16*)alloc_b((size_t)CB * 576 * HW * 2);
    if (off > ws_size) return;

    k_feats<<<BB * HW / 64, 256, 0, stream>>>(
        x, w_base, b_base, a_base, w_match, b_match, a_match, w_asm, b_asm, a_asm,
        mft, rft, base_f, mbss, rmss);
    k_nbr<<<(NTOT + 255) / 256, 256, 0, stream>>>(nbr_pos, zpad);
    k_qnorm<<<BB * HW / 256, 256, 0, stream>>>(mbss, qub);
    k_norms<<<(BB * NTOT + 255) / 256, 256, 0, stream>>>(rmss, nbr_pos, sinv);

    for (int b0 = 0; b0 < BB; b0 += CB) {
        k_corr_mfma<<<dim3(8, NT26, CB), 512, 0, stream>>>(
            mft, rft, nbr_pos, sinv, qub, zpad, tbuf, partS, b0);
        k_rowsum<<<CB * HW / 256, 256, 0, stream>>>(partS, fin);
        k_vgather<<<dim3(CC, CB), 256, 0, stream>>>(base_f, nbr_pos, Vb, b0);
        k_fold_mfma<<<dim3(8, 3, CB), 512, 0, stream>>>(Vb, tbuf, fin, outacc);
        k_epilogue<<<CB * CC * HW / 256, 256, 0, stream>>>(x, outacc, out, b0);
    }
}

// Round 19
// 510.752 us; speedup vs baseline: 1.0476x; 1.0476x over previous
//
#include <hip/hip_runtime.h>
#include <hip/hip_bf16.h>
#include <math.h>

#define BB 32
#define CC 64
#define C2 32
#define HH 32
#define WW 32
#define HW 1024
#define NTOT 3278
#define NPAD2 3328   // padded N (multiple of 128) for MFMA corr + fold
#define NT26 26      // NPAD2 / 128
#define NT64 52      // NPAD2 / 64  (k-tiles of the fold GEMM)

typedef __bf16   bf16x8 __attribute__((ext_vector_type(8)));
typedef _Float16 half8  __attribute__((ext_vector_type(8)));
typedef float    f32x4  __attribute__((ext_vector_type(4)));

__device__ __constant__ int SC_SIZE[5] = {32, 28, 25, 22, 19};
__device__ __constant__ int SC_OFF[6]  = {0, 1024, 1808, 2433, 2917, 3278};

// ---------------- fused feature kernel: LDS-staged, x read once ----------------
#define XS_STR 65
#define WS_STR 132
__global__ void __launch_bounds__(256, 1) k_feats(
        const float* __restrict__ x,
        const float* __restrict__ wb, const float* __restrict__ bb, const float* __restrict__ ab,
        const float* __restrict__ wm, const float* __restrict__ bm, const float* __restrict__ am,
        const float* __restrict__ wa, const float* __restrict__ ba, const float* __restrict__ aa,
        _Float16* __restrict__ mft, _Float16* __restrict__ rft,
        __bf16* __restrict__ basef,
        float* __restrict__ mbss, float* __restrict__ rmss) {
    __shared__ float Xs[64 * XS_STR];     // [c][p]
    __shared__ float Wls[64 * WS_STR];    // [c][o]
    __shared__ float bsh[128];
    __shared__ float ash3[3];
    int tid = threadIdx.x;
    int g0 = blockIdx.x * 64;
    int b = g0 >> 10, p0 = g0 & 1023;

    const float* xb = x + (size_t)b * CC * HW + p0;
    for (int i = tid; i < 64 * 64; i += 256) {
        int c = i >> 6, p = i & 63;
        Xs[c * XS_STR + p] = xb[(size_t)c * HW + p];
    }
    for (int i = tid; i < 128 * 64; i += 256) {
        int o = i >> 6, c = i & 63;
        float w = (o < 32) ? wb[o * CC + c] : (o < 64) ? wm[(o - 32) * CC + c] : wa[(o - 64) * CC + c];
        Wls[c * WS_STR + o] = w;
    }
    if (tid < 128) bsh[tid] = (tid < 32) ? bb[tid] : (tid < 64) ? bm[tid - 32] : ba[tid - 64];
    if (tid == 128) ash3[0] = ab[0];
    if (tid == 129) ash3[1] = am[0];
    if (tid == 130) ash3[2] = aa[0];
    __syncthreads();

    int p = tid & 63, og = tid >> 6;
    int o0 = og * 32;
    float acc[32];
#pragma unroll
    for (int oi = 0; oi < 32; ++oi) acc[oi] = bsh[o0 + oi];
    for (int c = 0; c < 64; ++c) {
        float xv = Xs[c * XS_STR + p];
        const float* wr = &Wls[c * WS_STR + o0];
#pragma unroll
        for (int oi = 0; oi < 32; ++oi) acc[oi] += wr[oi] * xv;
    }
    int pp = p0 + p;
    if (og < 2) {
        float alpha = ash3[og], ss = 0.f;
        half8 hv[4];
#pragma unroll
        for (int oi = 0; oi < 32; ++oi) {
            float v = acc[oi] >= 0.f ? acc[oi] : alpha * acc[oi];
            ss += v * v;
            hv[oi >> 3][oi & 7] = (_Float16)v;
        }
        _Float16* d = (og == 0 ? mft : rft) + ((size_t)b * HW + pp) * 32;
#pragma unroll
        for (int q = 0; q < 4; ++q) *(half8*)&d[q * 8] = hv[q];
        if (og == 0) mbss[(size_t)b * HW + pp] = ss;
        else         rmss[(size_t)b * HW + pp] = ss;
    } else {
        float alpha = ash3[2];
        int ob = o0 - 64;
#pragma unroll
        for (int oi = 0; oi < 32; ++oi) {
            float v = acc[oi] >= 0.f ? acc[oi] : alpha * acc[oi];
            basef[((size_t)b * CC + ob + oi) * HW + pp] = (__bf16)v;
        }
    }
}

// ---------------- neighbor table (+ zero pad for predicated gload_lds) ----------------
__global__ void k_nbr(int* __restrict__ nbr_pos, float* __restrict__ zpad) {
    if (blockIdx.x == 0 && threadIdx.x < 64) zpad[threadIdx.x] = 0.f;
    int n = blockIdx.x * blockDim.x + threadIdx.x;
    if (n >= NTOT) return;
    int s = 0;
    while (s < 4 && n >= SC_OFF[s + 1]) ++s;
    int q = n - SC_OFF[s];
    int hs = SC_SIZE[s];
    int ny = q / hs, nx = q % hs;
    for (int dy = 0; dy < 3; ++dy)
        for (int dx = 0; dx < 3; ++dx) {
            int yy = ny + dy - 1, xx = nx + dx - 1;
            int pos = -1;
            if (yy >= 0 && yy < hs && xx >= 0 && xx < hs)
                pos = ((yy * HH) / hs) * WW + (xx * WW) / hs;
            nbr_pos[(dy * 3 + dx) * NTOT + n] = pos;
        }
}

// ---------------- per-(b,p) logit upper bound ----------------
__global__ void k_qnorm(const float* __restrict__ mbss, float* __restrict__ qub) {
    int t = blockIdx.x * blockDim.x + threadIdx.x;
    int b = t >> 10, p = t & 1023;
    int y = p >> 5, x = p & 31;
    float s = 0.f;
#pragma unroll
    for (int dy = 0; dy < 3; ++dy)
#pragma unroll
        for (int dx = 0; dx < 3; ++dx) {
            int yy = y + dy - 1, xx = x + dx - 1;
            if (yy >= 0 && yy < HH && xx >= 0 && xx < WW)
                s += mbss[(size_t)b * HW + yy * WW + xx];
        }
    qub[t] = 10.0f * sqrtf(s);
}

// ---------------- per-(b,n) filter norms ----------------
__global__ void k_norms(const float* __restrict__ rmss, const int* __restrict__ nbr_pos,
                        float* __restrict__ sinv) {
    int t = blockIdx.x * blockDim.x + threadIdx.x;
    if (t >= BB * NTOT) return;
    int b = t / NTOT, n = t % NTOT;
    float sum = 0.f;
#pragma unroll
    for (int kk = 0; kk < 9; ++kk) {
        int pos = nbr_pos[kk * NTOT + n];
        if (pos >= 0) sum += rmss[(size_t)b * HW + pos];
    }
    sinv[t] = 10.0f / fmaxf(sqrtf(sum), 1e-4f);
}

// ---------------- V gather: LDS-staged basef row, tiled+swizzled Vb output ----------------
// Vb layout: Vb[((cb*NT64 + kt)*576 + m)*64 + j'] with j' = ((j/8) ^ (m&7))*8 + j%8
// R14 verified: XCD-affinity (cb -> XCD cb/(CB/8)) fills Vb into fold's L2.
__global__ void k_vgather(const __bf16* __restrict__ basef, const int* __restrict__ nbr_pos,
                          __bf16* __restrict__ Vb, int b0) {
    int c, cb;
    {
        int nCB = gridDim.y;
        int bid = blockIdx.x + CC * blockIdx.y;
        if ((nCB & 7) == 0) {
            int xcd = bid & 7, idx = bid >> 3;       // idx in [0, CC*nCB/8)
            int cpx = nCB >> 3;
            cb = xcd * cpx + idx / CC;
            c  = idx % CC;
        } else { c = blockIdx.x; cb = blockIdx.y; }
    }
    int tid = threadIdx.x;
    __shared__ __bf16 row[HW];    // one basef channel row, 2 KB
    const __bf16* src = basef + ((size_t)(b0 + cb) * CC + c) * HW;
    for (int i = tid; i < HW / 8; i += 256)
        *(bf16x8*)&row[i * 8] = *(const bf16x8*)&src[i * 8];
    __syncthreads();
    for (int t = tid; t < 9 * (NPAD2 / 8); t += 256) {
        int kk = t / (NPAD2 / 8), nq = t - kk * (NPAD2 / 8);
        int n0 = nq * 8;
        const int* nb = &nbr_pos[kk * NTOT];
        bf16x8 v8;
#pragma unroll
        for (int u = 0; u < 8; ++u) {
            int n = n0 + u;
            __bf16 v = (__bf16)0.f;
            if (n < NTOT) {
                int pos = nb[n];
                if (pos >= 0) v = row[pos];    // LDS gather, not global gather
            }
            v8[u] = v;
        }
        int m = c * 9 + kk;
        int nt = n0 >> 6;
        int j0s = (((n0 & 63) >> 3) ^ (m & 7)) << 3;
        *(bf16x8*)&Vb[(((size_t)cb * NT64 + nt) * 576 + m) * 64 + j0s] = v8;
    }
}

__device__ __forceinline__ void gload16(const void* g, void* l) {
    __builtin_amdgcn_global_load_lds(
        (const __attribute__((address_space(1))) void*)g,
        (__attribute__((address_space(3))) void*)l, 16, 0, 0);
}

// ---------------- correlation GEMM: fp16, 128p x 128n, DIRECT-STAGE gather ----------------
// R18 falsifier fired: 3-buffer counted-vmcnt regressed corr 82->89 (LDS 64KB
// dropped occupancy 55->38%; TLP loss > pipeline gain — same lesson as R2, at
// L2 latency). REVERTED to the R10/R14/R17-verified double-buffer form (best
// measured: corr ~82us). Corr ledger closed on both sides: {no-staging(R4),
// 128p-amortize(R7), small-LDS(R8), 3buf-vmcnt(R18)} all null/worse.
__global__ void __launch_bounds__(512) k_corr_mfma(
        const _Float16* __restrict__ mft, const _Float16* __restrict__ rft,
        const int* __restrict__ nbr_pos,
        const float* __restrict__ sinv, const float* __restrict__ qub,
        const float* __restrict__ zpad,
        __bf16* __restrict__ tbuf, float* __restrict__ partS, int b0) {
    int ptile, ntile, cb;
    {
        int nx = gridDim.x, ny = gridDim.y, nz = gridDim.z;     // 8, 26, CB
        int bid = blockIdx.x + nx * (blockIdx.y + ny * blockIdx.z);
        if ((nz & 7) == 0) {
            int xcd = bid & 7, idx = bid >> 3;
            int percb = nx * ny;               // 208
            int cpx = nz >> 3;
            cb = xcd * cpx + idx / percb;
            int r = idx % percb;
            ntile = r / nx;
            ptile = r % nx;
        } else { ptile = blockIdx.x; ntile = blockIdx.y; cb = blockIdx.z; }
    }
    int tid  = threadIdx.x;
    int lane = tid & 63, wave = tid >> 6;       // 8 waves
    int row16 = lane & 15, quad = lane >> 4;
    int wrP = wave >> 2, wrN = wave & 3;        // 2P x 4N wave grid (64p x 32n each)
    int p0 = ptile * 128, n0 = ntile * 128;

    __shared__ _Float16 Abuf[2][128 * 32];   // 2 x 8 KB  [row][32k], oct^(row&3) swizzle
    __shared__ _Float16 Bbuf[2][128 * 32];   // 2 x 8 KB
    __shared__ short nbrs[9][128];           // 2,304 B
    __shared__ short posA[9][128];           // 2,304 B
    __shared__ float sMub[128];              //   512 B
    __shared__ float redS[8][64];            // 2,048 B
    __shared__ __bf16 Tls[8][16 * 36];       // 9,216 B
                                             // total 49,152 B -> 3 blocks/CU

    if (tid < 128) sMub[tid] = qub[(size_t)(b0 + cb) * HW + p0 + tid];
    for (int i = tid; i < 9 * 128; i += 512) {
        int kk = i >> 7, j = i & 127;
        int n = n0 + j;
        nbrs[kk][j] = (short)((n < NTOT) ? nbr_pos[kk * NTOT + n] : -1);
        int pg = p0 + j;
        int py = (pg >> 5) + kk / 3 - 1, px = (pg & 31) + kk % 3 - 1;
        posA[kk][j] = (short)((py >= 0 && py < HH && px >= 0 && px < WW) ? (py * WW + px) : -1);
    }

    const char* mh = (const char*)(mft + (size_t)(b0 + cb) * HW * 32);
    const char* rh = (const char*)(rft + (size_t)(b0 + cb) * HW * 32);
    const char* zp = (const char*)zpad;

    f32x4 acc[4][2];
#pragma unroll
    for (int i = 0; i < 4; ++i)
#pragma unroll
        for (int j = 0; j < 2; ++j) acc[i][j] = (f32x4){0.f, 0.f, 0.f, 0.f};

    __syncthreads();   // tables ready (stage reads them from LDS)

    int srow = wave * 16 + (lane >> 2);          // this lane's staged row
    int sshift = (((lane & 3) ^ (srow & 3)) << 4);   // pre-swizzled src byte offset
    auto stageAB = [&](int sb, int kk) {
        int pa = posA[kk][srow];
        const char* sa = (pa >= 0) ? mh + (size_t)pa * 64 + sshift : zp;
        gload16(sa, (char*)&Abuf[sb][0] + wave * 1024);
        int pb = nbrs[kk][srow];
        const char* sbp = (pb >= 0) ? rh + (size_t)pb * 64 + sshift : zp;
        gload16(sbp, (char*)&Bbuf[sb][0] + wave * 1024);
    };

    stageAB(0, 0);
    __syncthreads();   // barrier drains vmcnt -> buf0 ready
    int cur = 0;
    for (int kk = 0; kk < 9; ++kk) {
        if (kk < 8) stageAB(cur ^ 1, kk + 1);   // in flight under ds_read+MFMA
        half8 af[4], bf[2];
#pragma unroll
        for (int m = 0; m < 4; ++m) {
            int row = wrP * 64 + m * 16 + row16;
            af[m] = *(const half8*)&Abuf[cur][row * 32 + ((quad ^ (row & 3)) << 3)];
        }
#pragma unroll
        for (int nb = 0; nb < 2; ++nb) {
            int row = wrN * 32 + nb * 16 + row16;
            bf[nb] = *(const half8*)&Bbuf[cur][row * 32 + ((quad ^ (row & 3)) << 3)];
        }
#pragma unroll
        for (int m = 0; m < 4; ++m)
#pragma unroll
            for (int nb = 0; nb < 2; ++nb)
                acc[m][nb] = __builtin_amdgcn_mfma_f32_16x16x32_f16(af[m], bf[nb], acc[m][nb], 0, 0, 0);
        __syncthreads();   // drains next-tile stage; frees buf cur
        cur ^= 1;
    }

    // ---- epilogue: v = acc*sinv[n]; t = exp(v - Mub[p]); Tls transpose -> 16B stores ----
    int nn[2];
    float sv[2];
    bool valid[2];
#pragma unroll
    for (int nb = 0; nb < 2; ++nb) {
        nn[nb] = n0 + wrN * 32 + nb * 16 + row16;
        valid[nb] = nn[nb] < NTOT;
        sv[nb] = valid[nb] ? sinv[(size_t)(b0 + cb) * NTOT + nn[nb]] : 0.f;
    }
    float sm[4][4];
#pragma unroll
    for (int m = 0; m < 4; ++m)
#pragma unroll
        for (int r = 0; r < 4; ++r) sm[m][r] = 0.f;

    int tr = lane >> 2, tc = (lane & 3) * 8;   // transpose-read coords (wave-local)
#pragma unroll
    for (int m = 0; m < 4; ++m) {
#pragma unroll
        for (int nb = 0; nb < 2; ++nb) {
#pragma unroll
            for (int r = 0; r < 4; ++r) {
                float mub = sMub[wrP * 64 + m * 16 + quad * 4 + r];
                float e = valid[nb] ? __expf(acc[m][nb][r] * sv[nb] - mub) : 0.f;
                Tls[wave][(quad * 4 + r) * 36 + nb * 16 + row16] = (__bf16)e;
                sm[m][r] += e;
            }
        }
        // wave-local consume (no block barrier needed)
        bf16x8 v = *(const bf16x8*)&Tls[wave][tr * 36 + tc];
        int nglob = n0 + wrN * 32 + tc;
        int nt = nglob >> 6, j0 = nglob & 63;
        int j0s = ((j0 >> 3) ^ (tr & 7)) << 3;   // p&7 == tr&7 (p0, wrP*64, m*16 all mult of 8)
        int p = p0 + wrP * 64 + m * 16 + tr;
        *(bf16x8*)&tbuf[(((size_t)cb * NT64 + nt) * HW + p) * 64 + j0s] = v;
    }

#pragma unroll
    for (int msk = 1; msk < 16; msk <<= 1)
#pragma unroll
        for (int m = 0; m < 4; ++m)
#pragma unroll
            for (int r = 0; r < 4; ++r) sm[m][r] += __shfl_xor(sm[m][r], msk, 64);
    if (row16 == 0)
#pragma unroll
        for (int m = 0; m < 4; ++m)
#pragma unroll
            for (int r = 0; r < 4; ++r) redS[wave][m * 16 + quad * 4 + r] = sm[m][r];
    __syncthreads();
    if ((wave == 0 || wave == 4) && row16 == 0) {
#pragma unroll
        for (int m = 0; m < 4; ++m)
#pragma unroll
            for (int r = 0; r < 4; ++r) {
                int p = m * 16 + quad * 4 + r;   // local within this wave's 64-p half
                float S = redS[wrP * 4 + 0][p] + redS[wrP * 4 + 1][p] +
                          redS[wrP * 4 + 2][p] + redS[wrP * 4 + 3][p];
                partS[((size_t)cb * HW + p0 + wrP * 64 + p) * NT26 + ntile] = S;
            }
    }
}

// ---------------- row sum reduce ----------------
__global__ void k_rowsum(const float* __restrict__ partS, float* __restrict__ fin) {
    int row = blockIdx.x * 256 + threadIdx.x;
    float s = 0.f;
#pragma unroll
    for (int nt = 0; nt < NT26; ++nt) s += partS[(size_t)row * NT26 + nt];
    fin[row] = 1.0f / fmaxf(s, 1e-38f);
}

// ---------------- fold GEMM (MFMA bf16), 192m x 128p + XCD-chunked swizzle ----------------
// FM=192 confirmed optimum (R16 A/B under affinity). Unchanged.
#define A_KSTRIDE (576 * 64 * 2)     // bytes per k-tile of Vb
#define B_KSTRIDE (1024 * 64 * 2)    // bytes per k-tile of tbuf
#define FM 192                        // fold tile m
#define FP 128                        // fold tile p

__global__ void __launch_bounds__(512, 4) k_fold_mfma(
        const __bf16* __restrict__ Vb, const __bf16* __restrict__ tbuf,
        const float* __restrict__ fin, __bf16* __restrict__ outacc) {
    int ptile, mtile, cb;
    {
        int nx = gridDim.x, ny = gridDim.y, nz = gridDim.z;
        int bid = blockIdx.x + nx * (blockIdx.y + ny * blockIdx.z);
        if ((nz & 7) == 0) {
            int xcd = bid & 7, idx = bid >> 3;
            int percb = nx * ny;              // blocks per cb (24)
            int cpx = nz >> 3;                // cbs per xcd
            cb = xcd * cpx + idx / percb;
            int r = idx % percb;
            mtile = r / nx;
            ptile = r % nx;
        } else {
            ptile = blockIdx.x; mtile = blockIdx.y; cb = blockIdx.z;
        }
    }
    int tid  = threadIdx.x;
    int lane = tid & 63, wave = tid >> 6;     // 8 waves
    int row16 = lane & 15, quad = lane >> 4;
    int wrM = wave >> 2, wrN = wave & 3;      // 2 x 4 wave grid: per-wave 96m x 32p

    __shared__ __bf16 Als[2][FM * 64];    // 2 x 24 KB
    __shared__ __bf16 Bls[2][FP * 64];    // 2 x 16 KB

    const char* Ag = (const char*)(Vb   + (((size_t)cb * NT64) * 576  + (size_t)mtile * FM) * 64);
    const char* Bg = (const char*)(tbuf + (((size_t)cb * NT64) * 1024 + (size_t)ptile * FP) * 64);

    f32x4 acc[6][2];
#pragma unroll
    for (int i = 0; i < 6; ++i)
#pragma unroll
        for (int j = 0; j < 2; ++j) acc[i][j] = (f32x4){0.f, 0.f, 0.f, 0.f};

    int lo16 = lane * 16;
    // A tile 24KB = 24 x 1KB chunks (8 rows each); B tile 16KB = 16 chunks.
    // 40 chunks / 8 waves = 5 per wave. Linear copy of pre-swizzled global.
    auto stage = [&](int sb, int kt) {
#pragma unroll
        for (int i = 0; i < 5; ++i) {
            int q = wave * 5 + i;
            if (q < 24) {
                gload16(Ag + (size_t)kt * A_KSTRIDE + q * 1024 + lo16,
                        (char*)&Als[sb][0] + q * 1024);
            } else {
                gload16(Bg + (size_t)kt * B_KSTRIDE + (q - 24) * 1024 + lo16,
                        (char*)&Bls[sb][0] + (q - 24) * 1024);
            }
        }
    };

    int sg = row16 & 7;   // row&7 for both A (m) and B (p) fragment rows
    auto compute = [&](int sb) {
#pragma unroll
        for (int kh = 0; kh < 2; ++kh) {
            int ko = ((kh * 4 + quad) ^ sg) << 3;
            bf16x8 af[6], bf[2];
#pragma unroll
            for (int mb = 0; mb < 6; ++mb)
                af[mb] = *(const bf16x8*)&Als[sb][(wrM * 96 + mb * 16 + row16) * 64 + ko];
#pragma unroll
            for (int pbi = 0; pbi < 2; ++pbi)
                bf[pbi] = *(const bf16x8*)&Bls[sb][(wrN * 32 + pbi * 16 + row16) * 64 + ko];
#pragma unroll
            for (int mb = 0; mb < 6; ++mb)
#pragma unroll
                for (int pbi = 0; pbi < 2; ++pbi)
                    acc[mb][pbi] = __builtin_amdgcn_mfma_f32_16x16x32_bf16(af[mb], bf[pbi], acc[mb][pbi], 0, 0, 0);
        }
    };

    stage(0, 0);
    __syncthreads();
    int cur = 0;
    for (int kt = 0; kt < NT64; ++kt) {
        if (kt + 1 < NT64) stage(cur ^ 1, kt + 1);   // in flight under ds_read+MFMA
        compute(cur);
        __syncthreads();   // drains vmcnt: next tile landed; buf cur free for kt+2
        cur ^= 1;
    }

    float fsc[2];
#pragma unroll
    for (int pbi = 0; pbi < 2; ++pbi)
        fsc[pbi] = fin[(size_t)cb * HW + ptile * FP + wrN * 32 + pbi * 16 + row16];
#pragma unroll
    for (int mb = 0; mb < 6; ++mb)
#pragma unroll
        for (int pbi = 0; pbi < 2; ++pbi) {
#pragma unroll
            for (int r = 0; r < 4; ++r) {
                int mg = mtile * FM + wrM * 96 + mb * 16 + quad * 4 + r;
                int pg = ptile * FP + wrN * 32 + pbi * 16 + row16;
                outacc[((size_t)cb * 576 + mg) * HW + pg] = (__bf16)(acc[mb][pbi][r] * fsc[pbi]);
            }
        }
}

// ---------------- epilogue (bf16 outacc) ----------------
// R14 verified: XCD-affinity so the 9-tap outacc reads hit fold's L2.
__global__ void k_epilogue(const float* __restrict__ x, const __bf16* __restrict__ outacc,
                           float* __restrict__ out, int b0) {
    int li, cb;
    {
        int nblk = gridDim.x;                 // CB * 256
        int nCB = nblk >> 8;
        int bid = blockIdx.x;
        if ((nCB & 7) == 0) {
            int xcd = bid & 7, idx = bid >> 3;    // idx in [0, nblk/8)
            int cpx = nCB >> 3;
            cb = xcd * cpx + idx / 256;
            li = (idx % 256) * 256 + threadIdx.x; // local index within cb
        } else {
            int t = bid * 256 + threadIdx.x;
            cb = t >> 16; li = t & 65535;
        }
    }
    int c = (li >> 10) & 63;
    int p = li & 1023;
    int b = b0 + cb;
    int y = p >> 5, xx = p & 31;
    float acc = 0.f;
#pragma unroll
    for (int ky = 0; ky < 3; ++ky)
#pragma unroll
        for (int kx = 0; kx < 3; ++kx) {
            int py = y + 1 - ky, px = xx + 1 - kx;
            if (py >= 0 && py < HH && px >= 0 && px < WW)
                acc += (float)outacc[((size_t)cb * 576 + c * 9 + ky * 3 + kx) * HW + py * WW + px];
        }
    size_t o = ((size_t)b * CC + c) * HW + p;
    out[o] = x[o] + 0.25f * acc;
}

extern "C" void kernel_launch(void* const* d_in, const int* in_sizes, int n_in,
                              void* d_out, int out_size, void* d_ws, size_t ws_size,
                              hipStream_t stream) {
    const float* x       = (const float*)d_in[0];
    const float* w_base  = (const float*)d_in[1];
    const float* b_base  = (const float*)d_in[2];
    const float* a_base  = (const float*)d_in[3];
    const float* w_match = (const float*)d_in[4];
    const float* b_match = (const float*)d_in[5];
    const float* a_match = (const float*)d_in[6];
    const float* w_asm   = (const float*)d_in[7];
    const float* b_asm   = (const float*)d_in[8];
    const float* a_asm   = (const float*)d_in[9];
    float* out = (float*)d_out;

    const size_t fixed = ((size_t)BB * HW * 32 * 2) * 2 + ((size_t)BB * CC * HW * 2) +
                         ((size_t)BB * HW * 4) * 3 + ((size_t)BB * NTOT * 4) +
                         ((size_t)9 * NTOT * 4) + 65536;
    const size_t perCB = ((size_t)HW * NPAD2 * 2) + ((size_t)HW * NT26 * 4) +
                         ((size_t)HW * 4) + ((size_t)576 * NPAD2 * 2) +
                         ((size_t)576 * HW * 2) + 65536;
    int CB = 32;
    while (CB > 1 && fixed + perCB * CB > ws_size) CB >>= 1;

    char* ws = (char*)d_ws;
    size_t off = 0;
    auto alloc_b = [&](size_t bytes) {
        void* p = (void*)(ws + off);
        off += bytes;
        off = (off + 255) & ~(size_t)255;
        return p;
    };
    _Float16* mft   = (_Float16*)alloc_b((size_t)BB * HW * 32 * 2);
    _Float16* rft   = (_Float16*)alloc_b((size_t)BB * HW * 32 * 2);
    __bf16* base_f  = (__bf16*)alloc_b((size_t)BB * CC * HW * 2);
    float*  mbss    = (float*)alloc_b((size_t)BB * HW * 4);
    float*  rmss    = (float*)alloc_b((size_t)BB * HW * 4);
    float*  qub     = (float*)alloc_b((size_t)BB * HW * 4);
    float*  sinv    = (float*)alloc_b((size_t)BB * NTOT * 4);
    int*    nbr_pos = (int*)alloc_b((size_t)9 * NTOT * 4);
    float*  zpad    = (float*)alloc_b(256);
    __bf16* tbuf    = (__bf16*)alloc_b((size_t)CB * HW * NPAD2 * 2);
    float*  partS   = (float*)alloc_b((size_t)CB * HW * NT26 * 4);
    float*  fin     = (float*)alloc_b((size_t)CB * HW * 4);
    __bf16* Vb      = (__bf16*)alloc_b((size_t)CB * 576 * NPAD2 * 2);
    __bf16* outacc  = (__bf16*)alloc_b((size_t)CB * 576 * HW * 2);
    if (off > ws_size) return;

    k_feats<<<BB * HW / 64, 256, 0, stream>>>(
        x, w_base, b_base, a_base, w_match, b_match, a_match, w_asm, b_asm, a_asm,
        mft, rft, base_f, mbss, rmss);
    k_nbr<<<(NTOT + 255) / 256, 256, 0, stream>>>(nbr_pos, zpad);
    k_qnorm<<<BB * HW / 256, 256, 0, stream>>>(mbss, qub);
    k_norms<<<(BB * NTOT + 255) / 256, 256, 0, stream>>>(rmss, nbr_pos, sinv);

    for (int b0 = 0; b0 < BB; b0 += CB) {
        k_corr_mfma<<<dim3(8, NT26, CB), 512, 0, stream>>>(
            mft, rft, nbr_pos, sinv, qub, zpad, tbuf, partS, b0);
        k_rowsum<<<CB * HW / 256, 256, 0, stream>>>(partS, fin);
        k_vgather<<<dim3(CC, CB), 256, 0, stream>>>(base_f, nbr_pos, Vb, b0);
        k_fold_mfma<<<dim3(8, 3, CB), 512, 0, stream>>>(Vb, tbuf, fin, outacc);
        k_epilogue<<<CB * CC * HW / 256, 256, 0, stream>>>(x, outacc, out, b0);
    }
}